// Round 4
// baseline (301.531 us; speedup 1.0000x reference)
//
#include <hip/hip_runtime.h>

#define B_ROWS 2048
#define N_GLB  65536
#define DDIM   128
#define NCLUST 100
#define INV_T  (1.0f/0.07f)
#define LOG2E  1.4426950408889634f
#define LN2    0.6931471805599453f
#define NSPLIT 16
#define CHUNK_COLS (N_GLB/NSPLIT)   // 4096
#define ITERS (CHUNK_COLS/64)       // 64 iters, 64 cols per block-iter (16/wave)
#define TOPK 10
#define CAP  256
#define CAPC 2048                   // bucket capacity per cluster (mean 655, 54 sigma)
#define TAU_L2E (3.7881f*LOG2E)     // 3.0 sigma threshold, in log2e units
#define CSC    65536.0f             // csum fixed-point scale 2^16
#define INV_CSC (1.0f/65536.0f)

typedef __attribute__((ext_vector_type(8))) short sh8;
typedef __attribute__((ext_vector_type(4))) float f32x4;
typedef unsigned long long u64;

__device__ __forceinline__ unsigned f2bf(float x) {
  unsigned u = __float_as_uint(x);
  u += 0x7fffu + ((u >> 16) & 1u);   // RNE
  return u >> 16;
}
__device__ __forceinline__ unsigned fmono(float v) {  // order-preserving f32->u32
  unsigned u = __float_as_uint(v);
  return ((int)u < 0) ? ~u : (u | 0x80000000u);
}
__device__ __forceinline__ float fmono_inv(unsigned m) {
  unsigned u = (m & 0x80000000u) ? (m & 0x7FFFFFFFu) : ~m;
  return __uint_as_float(u);
}
__device__ __forceinline__ u64 mkkey(float val, int col) {
  return ((u64)fmono(val) << 32) | (unsigned)(~(unsigned)col);
}
__device__ __forceinline__ u64 umax64(u64 a, u64 b) { return a > b ? a : b; }

// ---- prep: normalize, bf16-convert, write fragment-direct layout ----
// layout: row r, dim k: byte = (r>>4)*4096 + (k>>3)*256 + (r&15)*16 + (k&7)*2
__global__ void prep_kernel(const float* __restrict__ f, const float* __restrict__ g,
                            char* __restrict__ wsf2, char* __restrict__ wsg2,
                            float* __restrict__ inv_fT, float* __restrict__ inv_g) {
  int row = (blockIdx.x * blockDim.x + threadIdx.x) >> 6;
  int lane = threadIdx.x & 63;
  if (row >= B_ROWS + N_GLB) return;
  bool isf = row < B_ROWS;
  int rr = isf ? row : row - B_ROWS;
  const float* src = (isf ? f : g) + (size_t)rr * DDIM;
  float2 v = ((const float2*)src)[lane];               // dims 2*lane, 2*lane+1
  float ss = v.x * v.x + v.y * v.y;
  #pragma unroll
  for (int m = 32; m; m >>= 1) ss += __shfl_xor(ss, m);
  float inv = 1.0f / fmaxf(sqrtf(ss), 1e-12f);
  if (lane == 0) { if (isf) inv_fT[rr] = inv * INV_T; else inv_g[rr] = inv; }
  float sc = isf ? inv * (INV_T * LOG2E) : inv;        // fold 1/T and log2e into f
  unsigned pk = f2bf(v.x * sc) | (f2bf(v.y * sc) << 16);
  char* base = isf ? wsf2 : wsg2;
  *(unsigned*)(base + (size_t)(rr >> 4) * 4096 + (size_t)(lane >> 2) * 256
               + (size_t)(rr & 15) * 16 + (size_t)(lane & 3) * 4) = pk;
}

// ---- bucket build: scatter row ids into per-cluster lists ----
__global__ void bucket_kernel(const int* __restrict__ gclust,
                              int* __restrict__ bcnt, int* __restrict__ brow) {
  int r = blockIdx.x * 256 + threadIdx.x;
  if (r >= N_GLB) return;
  int c = gclust[r];
  int slot = atomicAdd(&bcnt[c], 1);
  if (slot < CAPC) brow[c * CAPC + slot] = r;
}

// ---- cluster sums from buckets: dense, pipelined, order-independent (int) ----
__global__ __launch_bounds__(256) void csum_kernel(const float* __restrict__ g,
                                                   const float* __restrict__ inv_g,
                                                   const int* __restrict__ bcnt,
                                                   const int* __restrict__ brow,
                                                   int* __restrict__ csum_i32,
                                                   int* __restrict__ hist) {
  int c = blockIdx.x;                 // 100 blocks, one per cluster
  int t = threadIdx.x;
  int d = t & 127, h = t >> 7;        // dim, half
  int n = min(bcnt[c], CAPC);
  int acc = 0;
  for (int i = h; i < n; i += 2) {
    int r = brow[c * CAPC + i];
    acc += (int)rintf(g[(size_t)r * DDIM + d] * inv_g[r] * CSC);  // per-elem quantize -> order-free
  }
  atomicAdd(&csum_i32[c * DDIM + d], acc);   // 2 int atomics per (c,d): deterministic
  if (t == 0) hist[c] = n;
}

// ---- sim: no-LDS MFMA GEMM + fused exp-sum + threshold push ----
#define PUSHQ(av, mm, q)                                                        \
  if ((av) > TAU_L2E) {                                                         \
    int rw = r0 + (mm) * 16 + lhi * 4 + (q);                                    \
    int slot = atomicAdd(&cnt[rw], 1);                                          \
    if (slot < CAP) { lv[rw * CAP + slot] = (av) * LN2; li[rw * CAP + slot] = colv; } \
  }

#define EPI(a, mm)                                                              \
  {                                                                             \
    se[mm].x += exp2f(a.x); se[mm].y += exp2f(a.y);                             \
    se[mm].z += exp2f(a.z); se[mm].w += exp2f(a.w);                             \
    float mx = fmaxf(fmaxf(a.x, a.y), fmaxf(a.z, a.w));                         \
    if (mx > TAU_L2E) { PUSHQ(a.x, mm, 0) PUSHQ(a.y, mm, 1) PUSHQ(a.z, mm, 2) PUSHQ(a.w, mm, 3) } \
  }

#define LOADB(dst, gptr)                                                        \
  { _Pragma("unroll") for (int s = 0; s < 4; ++s)                               \
      dst[s] = *(const uint4*)((gptr) + s * 1024 + (size_t)lane * 16); }

#define COMPUTE(bb, itv)                                                        \
  {                                                                             \
    f32x4 ac0 = {0,0,0,0}, ac1 = {0,0,0,0}, ac2 = {0,0,0,0}, ac3 = {0,0,0,0};   \
    _Pragma("unroll") for (int s = 0; s < 4; ++s) {                             \
      sh8 bs = __builtin_bit_cast(sh8, bb[s]);                                  \
      ac0 = __builtin_amdgcn_mfma_f32_16x16x32_bf16(afr[0][s], bs, ac0, 0, 0, 0); \
      ac1 = __builtin_amdgcn_mfma_f32_16x16x32_bf16(afr[1][s], bs, ac1, 0, 0, 0); \
      ac2 = __builtin_amdgcn_mfma_f32_16x16x32_bf16(afr[2][s], bs, ac2, 0, 0, 0); \
      ac3 = __builtin_amdgcn_mfma_f32_16x16x32_bf16(afr[3][s], bs, ac3, 0, 0, 0); \
    }                                                                           \
    const int colv = chunk * CHUNK_COLS + (itv) * 64 + w * 16 + l15;            \
    EPI(ac0, 0) EPI(ac1, 1) EPI(ac2, 2) EPI(ac3, 3)                             \
  }

__global__ __launch_bounds__(256, 3) void sim_kernel(
    const char* __restrict__ wsf2, const char* __restrict__ wsg2,
    float* __restrict__ p_se, float* __restrict__ lv, int* __restrict__ li,
    int* __restrict__ cnt) {
  __shared__ float sered[4][64];
  const int t = threadIdx.x, lane = t & 63, w = t >> 6;
  const int l15 = lane & 15, lhi = lane >> 4;
  const int chunk = blockIdx.x;          // 0..15
  const int r0 = blockIdx.y * 64;

  // hoist A fragments: 64 f-rows x 128 K in regs (16 x sh8 = 64 VGPR)
  const char* fbase = wsf2 + (size_t)(r0 >> 4) * 4096;
  sh8 afr[4][4];
  #pragma unroll
  for (int m = 0; m < 4; ++m)
    #pragma unroll
    for (int s = 0; s < 4; ++s)
      afr[m][s] = *(const sh8*)(fbase + (size_t)m * 4096 + s * 1024 + (size_t)lane * 16);

  f32x4 z = {0.f, 0.f, 0.f, 0.f};
  f32x4 se[4] = {z, z, z, z};

  const char* gb = wsg2 + (size_t)(chunk * 256 + w) * 4096;
  uint4 b0[4], b1[4];
  LOADB(b0, gb)
  for (int it = 0; it < ITERS; it += 2) {
    LOADB(b1, gb + 4 * 4096)
    COMPUTE(b0, it)
    if (it + 2 < ITERS) { LOADB(b0, gb + 8 * 4096) }
    COMPUTE(b1, it + 1)
    gb += 8 * 4096;
  }

  #pragma unroll
  for (int m = 0; m < 4; ++m)
    #pragma unroll
    for (int q = 0; q < 4; ++q) {
      float s = se[m][q];
      s += __shfl_xor(s, 1); s += __shfl_xor(s, 2);
      s += __shfl_xor(s, 4); s += __shfl_xor(s, 8);
      if (l15 == 0) sered[w][m * 16 + lhi * 4 + q] = s;
    }
  __syncthreads();
  if (t < 64) {
    float s = sered[0][t] + sered[1][t] + sered[2][t] + sered[3][t];
    p_se[(size_t)(r0 + t) * NSPLIT + chunk] = s;
  }
}

// ---- merge: per-row (one wave) se, cluster dot, exact top-10 from candidate list ----
__global__ __launch_bounds__(256) void merge_kernel(
    const float* __restrict__ f, const int* __restrict__ fclust,
    const int* __restrict__ gclust, const float* __restrict__ inv_fT,
    const float* __restrict__ p_se, const int* __restrict__ csum_i32,
    const int* __restrict__ hist, const float* __restrict__ lv,
    const int* __restrict__ li, const int* __restrict__ cnt,
    int* __restrict__ flags, float* __restrict__ rowv) {
  const int lane = threadIdx.x & 63, w = threadIdx.x >> 6;
  const int r = blockIdx.x * 4 + w;

  float sev = (lane < NSPLIT) ? p_se[(size_t)r * NSPLIT + lane] : 0.f;
  sev += __shfl_xor(sev, 8); sev += __shfl_xor(sev, 4);
  sev += __shfl_xor(sev, 2); sev += __shfl_xor(sev, 1);
  sev = __shfl(sev, 0);

  int rc = fclust[r];
  float2 fv = ((const float2*)(f + (size_t)r * DDIM))[lane];
  float sc = inv_fT[r];
  float dt = fv.x * sc * (csum_i32[rc * DDIM + 2 * lane] * INV_CSC)
           + fv.y * sc * (csum_i32[rc * DDIM + 2 * lane + 1] * INV_CSC);
  #pragma unroll
  for (int m = 32; m; m >>= 1) dt += __shfl_xor(dt, m);
  dt = __shfl(dt, 0);

  float Cc = (float)hist[rc];
  int n = cnt[r];
  bool bad = (n < TOPK) || (n > CAP);
  float S10 = 0.f, C10 = 0.f;
  if (!bad) {
    u64 k0 = 0, k1 = 0, k2 = 0, k3 = 0;
    int e = lane;
    if (e < n) k0 = mkkey(lv[(size_t)r * CAP + e], li[(size_t)r * CAP + e]);
    e = lane + 64;
    if (e < n) k1 = mkkey(lv[(size_t)r * CAP + e], li[(size_t)r * CAP + e]);
    e = lane + 128;
    if (e < n) k2 = mkkey(lv[(size_t)r * CAP + e], li[(size_t)r * CAP + e]);
    e = lane + 192;
    if (e < n) k3 = mkkey(lv[(size_t)r * CAP + e], li[(size_t)r * CAP + e]);
    for (int it = 0; it < TOPK; ++it) {
      u64 best = umax64(umax64(k0, k1), umax64(k2, k3));
      #pragma unroll
      for (int m = 32; m; m >>= 1) best = umax64(best, __shfl_xor(best, m));
      float val = fmono_inv((unsigned)(best >> 32));
      int col = (int)(~(unsigned)(best & 0xFFFFFFFFull));
      int gc = gclust[col];
      if (gc != rc) { S10 += val; C10 += 1.f; }
      if (k0 == best) k0 = 0;
      if (k1 == best) k1 = 0;
      if (k2 == best) k2 = 0;
      if (k3 == best) k3 = 0;
    }
  }
  if (lane == 0) {
    flags[r] = bad ? 1 : 0;
    if (!bad) {
      float L = logf(sev + 1e-12f);
      float C = Cc + C10;
      rowv[r] = (dt + S10 - C * L) / (C + 1e-12f);
    }
  }
}

// ---- fallback: exact top-10 by full recompute for flagged rows (normally none) ----
__global__ __launch_bounds__(256) void fallback_kernel(
    const float* __restrict__ f, const int* __restrict__ fclust,
    const int* __restrict__ gclust, const float* __restrict__ inv_fT,
    const float* __restrict__ p_se, const int* __restrict__ csum_i32,
    const int* __restrict__ hist, const char* __restrict__ wsf2,
    const char* __restrict__ wsg2, const int* __restrict__ flags,
    float* __restrict__ rowv) {
  const int lane = threadIdx.x & 63, w = threadIdx.x >> 6;
  const int r = blockIdx.x * 4 + w;
  if (flags[r] == 0) return;

  uint4 fr[16];
  #pragma unroll
  for (int c = 0; c < 16; ++c)
    fr[c] = *(const uint4*)(wsf2 + (size_t)(r >> 4) * 4096 + c * 256 + (size_t)(r & 15) * 16);

  u64 tk[TOPK];
  #pragma unroll
  for (int i = 0; i < TOPK; ++i) tk[i] = 0;

  for (int col = lane; col < N_GLB; col += 64) {
    const char* gp = wsg2 + (size_t)(col >> 4) * 4096 + (size_t)(col & 15) * 16;
    float acc = 0.f;
    #pragma unroll
    for (int c = 0; c < 16; ++c) {
      uint4 gv = *(const uint4*)(gp + c * 256);
      uint4 fc = fr[c];
      #pragma unroll
      for (int p = 0; p < 4; ++p) {
        unsigned fa = (&fc.x)[p], ga = (&gv.x)[p];
        acc += __uint_as_float(fa << 16) * __uint_as_float(ga << 16)
             + __uint_as_float(fa & 0xFFFF0000u) * __uint_as_float(ga & 0xFFFF0000u);
      }
    }
    u64 key = mkkey(acc, col);
    if (key > tk[0]) {
      u64 cur = key;
      #pragma unroll
      for (int i = 0; i < TOPK - 1; ++i) {
        u64 nxt = tk[i + 1];
        u64 lo = cur < nxt ? cur : nxt;
        u64 hi = cur < nxt ? nxt : cur;
        tk[i] = lo; cur = hi;
      }
      tk[TOPK - 1] = cur;
    }
  }

  int rc = fclust[r];
  float S10 = 0.f, C10 = 0.f;
  for (int it = 0; it < TOPK; ++it) {
    u64 best = tk[TOPK - 1];
    #pragma unroll
    for (int m = 32; m; m >>= 1) best = umax64(best, __shfl_xor(best, m));
    float val = fmono_inv((unsigned)(best >> 32)) * LN2;
    int col = (int)(~(unsigned)(best & 0xFFFFFFFFull));
    if (gclust[col] != rc) { S10 += val; C10 += 1.f; }
    if (tk[TOPK - 1] == best) {
      #pragma unroll
      for (int i = TOPK - 1; i > 0; --i) tk[i] = tk[i - 1];
      tk[0] = 0;
    }
  }

  float sev = (lane < NSPLIT) ? p_se[(size_t)r * NSPLIT + lane] : 0.f;
  sev += __shfl_xor(sev, 8); sev += __shfl_xor(sev, 4);
  sev += __shfl_xor(sev, 2); sev += __shfl_xor(sev, 1);
  sev = __shfl(sev, 0);
  float2 fv = ((const float2*)(f + (size_t)r * DDIM))[lane];
  float scf = inv_fT[r];
  float dt = fv.x * scf * (csum_i32[rc * DDIM + 2 * lane] * INV_CSC)
           + fv.y * scf * (csum_i32[rc * DDIM + 2 * lane + 1] * INV_CSC);
  #pragma unroll
  for (int m = 32; m; m >>= 1) dt += __shfl_xor(dt, m);
  if (lane == 0) {
    float L = logf(sev + 1e-12f);
    float C = (float)hist[rc] + C10;
    rowv[r] = (dt + S10 - C * L) / (C + 1e-12f);
  }
}

__global__ void final_kernel(const float* __restrict__ rowv, float* __restrict__ out) {
  __shared__ float sm[256];
  int t = threadIdx.x;
  float s = 0.f;
  for (int i = t; i < B_ROWS; i += 256) s += rowv[i];
  sm[t] = s;
  __syncthreads();
  for (int o = 128; o; o >>= 1) { if (t < o) sm[t] += sm[t + o]; __syncthreads(); }
  if (t == 0) out[0] = -(sm[0] / (float)B_ROWS);
}

extern "C" void kernel_launch(void* const* d_in, const int* in_sizes, int n_in,
                              void* d_out, int out_size, void* d_ws, size_t ws_size,
                              hipStream_t stream) {
  const float* f  = (const float*)d_in[0];
  const int*   fc = (const int*)  d_in[1];
  const float* g  = (const float*)d_in[2];
  const int*   gc = (const int*)  d_in[3];
  float* out = (float*)d_out;

  char* ws = (char*)d_ws;
  char*  wsf2    = ws;                          // 512 KB
  char*  wsg2    = ws + 524288;                 // 16 MB
  float* inv_fT  = (float*)(ws + 17301504);     // 8 KB
  float* inv_g   = (float*)(ws + 17309696);     // 256 KB
  float* p_se    = (float*)(ws + 17571840);     // 128 KB
  int*   csum_i32= (int*)  (ws + 17702912);     // 51.2 KB ─┐ zeroed
  int*   hist    = (int*)  (ws + 17754112);     // 512 B     │
  int*   cnt     = (int*)  (ws + 17754624);     // 8 KB      │
  int*   flags   = (int*)  (ws + 17762816);     // 8 KB      │
  int*   bcnt    = (int*)  (ws + 17771008);     // 512 B    ─┘ (69120 B total)
  float* lv      = (float*)(ws + 17840128);     // 2 MB
  int*   li      = (int*)  (ws + 19937280);     // 2 MB
  float* rowv    = (float*)(ws + 22034432);     // 8 KB
  int*   brow    = (int*)lv;                    // 800 KB overlay: dead before sim writes lv

  hipMemsetAsync(ws + 17702912, 0, 69120, stream);

  bucket_kernel<<<N_GLB / 256, 256, 0, stream>>>(gc, bcnt, brow);
  prep_kernel<<<(B_ROWS + N_GLB) / 4, 256, 0, stream>>>(f, g, wsf2, wsg2, inv_fT, inv_g);
  csum_kernel<<<NCLUST, 256, 0, stream>>>(g, inv_g, bcnt, brow, csum_i32, hist);

  dim3 grid(NSPLIT, B_ROWS / 64);   // x=chunk, y=row-block
  sim_kernel<<<grid, 256, 0, stream>>>(wsf2, wsg2, p_se, lv, li, cnt);

  merge_kernel<<<B_ROWS / 4, 256, 0, stream>>>(f, fc, gc, inv_fT, p_se, csum_i32,
                                               hist, lv, li, cnt, flags, rowv);
  fallback_kernel<<<B_ROWS / 4, 256, 0, stream>>>(f, fc, gc, inv_fT, p_se, csum_i32,
                                                  hist, wsf2, wsg2, flags, rowv);
  final_kernel<<<1, 256, 0, stream>>>(rowv, out);
}

// Round 5
// 186.465 us; speedup vs baseline: 1.6171x; 1.6171x over previous
//
#include <hip/hip_runtime.h>

#define B_ROWS 2048
#define N_GLB  65536
#define DDIM   128
#define NCLUST 100
#define INV_T  (1.0f/0.07f)
#define LOG2E  1.4426950408889634f
#define LN2    0.6931471805599453f
#define NSPLIT 16
#define CHUNK_COLS (N_GLB/NSPLIT)   // 4096
#define ITERS (CHUNK_COLS/64)       // 64 iters, 64 cols per block-iter (16/wave)
#define TOPK 10
#define CAP  256
#define NSLICE 8                    // csum contention slices
#define TAU_L2E (3.7881f*LOG2E)     // 3.0 sigma threshold, in log2e units
#define CSC    65536.0f             // csum fixed-point scale 2^16
#define INV_CSC (1.0f/65536.0f)

typedef __attribute__((ext_vector_type(8))) short sh8;
typedef __attribute__((ext_vector_type(4))) float f32x4;
typedef unsigned long long u64;

__device__ __forceinline__ unsigned f2bf(float x) {
  unsigned u = __float_as_uint(x);
  u += 0x7fffu + ((u >> 16) & 1u);   // RNE
  return u >> 16;
}
__device__ __forceinline__ unsigned fmono(float v) {  // order-preserving f32->u32
  unsigned u = __float_as_uint(v);
  return ((int)u < 0) ? ~u : (u | 0x80000000u);
}
__device__ __forceinline__ float fmono_inv(unsigned m) {
  unsigned u = (m & 0x80000000u) ? (m & 0x7FFFFFFFu) : ~m;
  return __uint_as_float(u);
}
__device__ __forceinline__ u64 mkkey(float val, int col) {
  return ((u64)fmono(val) << 32) | (unsigned)(~(unsigned)col);
}
__device__ __forceinline__ u64 umax64(u64 a, u64 b) { return a > b ? a : b; }

// ---- prep: normalize, bf16-convert, fragment-direct layout, fused cluster sums ----
// layout: row r, dim k: byte = (r>>4)*4096 + (k>>3)*256 + (r&15)*16 + (k&7)*2
// csum folded in: per g-row int fixed-point atomics into 1-of-8 slices (row&7).
// int adds commute -> deterministic regardless of atomic order.
__global__ void prep_kernel(const float* __restrict__ f, const float* __restrict__ g,
                            const int* __restrict__ gclust,
                            char* __restrict__ wsf2, char* __restrict__ wsg2,
                            float* __restrict__ inv_fT,
                            int* __restrict__ csum_i32, int* __restrict__ hist8) {
  int row = (blockIdx.x * blockDim.x + threadIdx.x) >> 6;
  int lane = threadIdx.x & 63;
  if (row >= B_ROWS + N_GLB) return;
  bool isf = row < B_ROWS;
  int rr = isf ? row : row - B_ROWS;
  const float* src = (isf ? f : g) + (size_t)rr * DDIM;
  float2 v = ((const float2*)src)[lane];               // dims 2*lane, 2*lane+1
  float ss = v.x * v.x + v.y * v.y;
  #pragma unroll
  for (int m = 32; m; m >>= 1) ss += __shfl_xor(ss, m);
  float inv = 1.0f / fmaxf(sqrtf(ss), 1e-12f);
  if (isf) {
    if (lane == 0) inv_fT[rr] = inv * INV_T;
  } else {
    int c = gclust[rr];
    int slice = rr & (NSLICE - 1);
    int* cp = csum_i32 + (size_t)slice * NCLUST * DDIM + c * DDIM + 2 * lane;
    atomicAdd(cp,     (int)rintf(v.x * inv * CSC));
    atomicAdd(cp + 1, (int)rintf(v.y * inv * CSC));
    if (lane == 0) atomicAdd(&hist8[slice * 128 + c], 1);
  }
  float sc = isf ? inv * (INV_T * LOG2E) : inv;        // fold 1/T and log2e into f
  unsigned pk = f2bf(v.x * sc) | (f2bf(v.y * sc) << 16);
  char* base = isf ? wsf2 : wsg2;
  *(unsigned*)(base + (size_t)(rr >> 4) * 4096 + (size_t)(lane >> 2) * 256
               + (size_t)(rr & 15) * 16 + (size_t)(lane & 3) * 4) = pk;
}

// ---- sim: no-LDS MFMA GEMM + fused exp-sum + threshold push ----
#define PUSHQ(av, mm, q)                                                        \
  if ((av) > TAU_L2E) {                                                         \
    int rw = r0 + (mm) * 16 + lhi * 4 + (q);                                    \
    int slot = atomicAdd(&cnt[rw], 1);                                          \
    if (slot < CAP) { lv[rw * CAP + slot] = (av) * LN2; li[rw * CAP + slot] = colv; } \
  }

#define EPI(a, mm)                                                              \
  {                                                                             \
    se[mm].x += exp2f(a.x); se[mm].y += exp2f(a.y);                             \
    se[mm].z += exp2f(a.z); se[mm].w += exp2f(a.w);                             \
    float mx = fmaxf(fmaxf(a.x, a.y), fmaxf(a.z, a.w));                         \
    if (mx > TAU_L2E) { PUSHQ(a.x, mm, 0) PUSHQ(a.y, mm, 1) PUSHQ(a.z, mm, 2) PUSHQ(a.w, mm, 3) } \
  }

#define LOADB(dst, gptr)                                                        \
  { _Pragma("unroll") for (int s = 0; s < 4; ++s)                               \
      dst[s] = *(const uint4*)((gptr) + s * 1024 + (size_t)lane * 16); }

#define COMPUTE(bb, itv)                                                        \
  {                                                                             \
    f32x4 ac0 = {0,0,0,0}, ac1 = {0,0,0,0}, ac2 = {0,0,0,0}, ac3 = {0,0,0,0};   \
    _Pragma("unroll") for (int s = 0; s < 4; ++s) {                             \
      sh8 bs = __builtin_bit_cast(sh8, bb[s]);                                  \
      ac0 = __builtin_amdgcn_mfma_f32_16x16x32_bf16(afr[0][s], bs, ac0, 0, 0, 0); \
      ac1 = __builtin_amdgcn_mfma_f32_16x16x32_bf16(afr[1][s], bs, ac1, 0, 0, 0); \
      ac2 = __builtin_amdgcn_mfma_f32_16x16x32_bf16(afr[2][s], bs, ac2, 0, 0, 0); \
      ac3 = __builtin_amdgcn_mfma_f32_16x16x32_bf16(afr[3][s], bs, ac3, 0, 0, 0); \
    }                                                                           \
    const int colv = chunk * CHUNK_COLS + (itv) * 64 + w * 16 + l15;            \
    EPI(ac0, 0) EPI(ac1, 1) EPI(ac2, 2) EPI(ac3, 3)                             \
  }

__global__ __launch_bounds__(256, 3) void sim_kernel(
    const char* __restrict__ wsf2, const char* __restrict__ wsg2,
    float* __restrict__ p_se, float* __restrict__ lv, int* __restrict__ li,
    int* __restrict__ cnt) {
  __shared__ float sered[4][64];
  const int t = threadIdx.x, lane = t & 63, w = t >> 6;
  const int l15 = lane & 15, lhi = lane >> 4;
  const int chunk = blockIdx.x;          // 0..15
  const int r0 = blockIdx.y * 64;

  // hoist A fragments: 64 f-rows x 128 K in regs (16 x sh8 = 64 VGPR)
  const char* fbase = wsf2 + (size_t)(r0 >> 4) * 4096;
  sh8 afr[4][4];
  #pragma unroll
  for (int m = 0; m < 4; ++m)
    #pragma unroll
    for (int s = 0; s < 4; ++s)
      afr[m][s] = *(const sh8*)(fbase + (size_t)m * 4096 + s * 1024 + (size_t)lane * 16);

  f32x4 z = {0.f, 0.f, 0.f, 0.f};
  f32x4 se[4] = {z, z, z, z};

  const char* gb = wsg2 + (size_t)(chunk * 256 + w) * 4096;
  uint4 b0[4], b1[4];
  LOADB(b0, gb)
  for (int it = 0; it < ITERS; it += 2) {
    LOADB(b1, gb + 4 * 4096)
    COMPUTE(b0, it)
    if (it + 2 < ITERS) { LOADB(b0, gb + 8 * 4096) }
    COMPUTE(b1, it + 1)
    gb += 8 * 4096;
  }

  #pragma unroll
  for (int m = 0; m < 4; ++m)
    #pragma unroll
    for (int q = 0; q < 4; ++q) {
      float s = se[m][q];
      s += __shfl_xor(s, 1); s += __shfl_xor(s, 2);
      s += __shfl_xor(s, 4); s += __shfl_xor(s, 8);
      if (l15 == 0) sered[w][m * 16 + lhi * 4 + q] = s;
    }
  __syncthreads();
  if (t < 64) {
    float s = sered[0][t] + sered[1][t] + sered[2][t] + sered[3][t];
    p_se[(size_t)(r0 + t) * NSPLIT + chunk] = s;
  }
}

// ---- merge: per-row (one wave) se, cluster dot, exact top-10 from candidate list ----
__global__ __launch_bounds__(256) void merge_kernel(
    const float* __restrict__ f, const int* __restrict__ fclust,
    const int* __restrict__ gclust, const float* __restrict__ inv_fT,
    const float* __restrict__ p_se, const int* __restrict__ csum_i32,
    const int* __restrict__ hist8, const float* __restrict__ lv,
    const int* __restrict__ li, const int* __restrict__ cnt,
    int* __restrict__ flags, float* __restrict__ rowv) {
  const int lane = threadIdx.x & 63, w = threadIdx.x >> 6;
  const int r = blockIdx.x * 4 + w;

  float sev = (lane < NSPLIT) ? p_se[(size_t)r * NSPLIT + lane] : 0.f;
  sev += __shfl_xor(sev, 8); sev += __shfl_xor(sev, 4);
  sev += __shfl_xor(sev, 2); sev += __shfl_xor(sev, 1);
  sev = __shfl(sev, 0);

  int rc = fclust[r];
  float2 fv = ((const float2*)(f + (size_t)r * DDIM))[lane];
  float sc = inv_fT[r];
  int ia = 0, ib = 0, hc = 0;
  #pragma unroll
  for (int s = 0; s < NSLICE; ++s) {
    ia += csum_i32[(size_t)s * NCLUST * DDIM + rc * DDIM + 2 * lane];
    ib += csum_i32[(size_t)s * NCLUST * DDIM + rc * DDIM + 2 * lane + 1];
    hc += hist8[s * 128 + rc];
  }
  float dt = fv.x * sc * (ia * INV_CSC) + fv.y * sc * (ib * INV_CSC);
  #pragma unroll
  for (int m = 32; m; m >>= 1) dt += __shfl_xor(dt, m);
  dt = __shfl(dt, 0);

  float Cc = (float)hc;
  int n = cnt[r];
  bool bad = (n < TOPK) || (n > CAP);
  float S10 = 0.f, C10 = 0.f;
  if (!bad) {
    u64 k0 = 0, k1 = 0, k2 = 0, k3 = 0;
    int e = lane;
    if (e < n) k0 = mkkey(lv[(size_t)r * CAP + e], li[(size_t)r * CAP + e]);
    e = lane + 64;
    if (e < n) k1 = mkkey(lv[(size_t)r * CAP + e], li[(size_t)r * CAP + e]);
    e = lane + 128;
    if (e < n) k2 = mkkey(lv[(size_t)r * CAP + e], li[(size_t)r * CAP + e]);
    e = lane + 192;
    if (e < n) k3 = mkkey(lv[(size_t)r * CAP + e], li[(size_t)r * CAP + e]);
    for (int it = 0; it < TOPK; ++it) {
      u64 best = umax64(umax64(k0, k1), umax64(k2, k3));
      #pragma unroll
      for (int m = 32; m; m >>= 1) best = umax64(best, __shfl_xor(best, m));
      float val = fmono_inv((unsigned)(best >> 32));
      int col = (int)(~(unsigned)(best & 0xFFFFFFFFull));
      int gc = gclust[col];
      if (gc != rc) { S10 += val; C10 += 1.f; }
      if (k0 == best) k0 = 0;
      if (k1 == best) k1 = 0;
      if (k2 == best) k2 = 0;
      if (k3 == best) k3 = 0;
    }
  }
  if (lane == 0) {
    flags[r] = bad ? 1 : 0;
    if (!bad) {
      float L = logf(sev + 1e-12f);
      float C = Cc + C10;
      rowv[r] = (dt + S10 - C * L) / (C + 1e-12f);
    }
  }
}

// ---- fallback: exact top-10 by full recompute for flagged rows (normally none) ----
__global__ __launch_bounds__(256) void fallback_kernel(
    const float* __restrict__ f, const int* __restrict__ fclust,
    const int* __restrict__ gclust, const float* __restrict__ inv_fT,
    const float* __restrict__ p_se, const int* __restrict__ csum_i32,
    const int* __restrict__ hist8, const char* __restrict__ wsf2,
    const char* __restrict__ wsg2, const int* __restrict__ flags,
    float* __restrict__ rowv) {
  const int lane = threadIdx.x & 63, w = threadIdx.x >> 6;
  const int r = blockIdx.x * 4 + w;
  if (flags[r] == 0) return;

  uint4 fr[16];
  #pragma unroll
  for (int c = 0; c < 16; ++c)
    fr[c] = *(const uint4*)(wsf2 + (size_t)(r >> 4) * 4096 + c * 256 + (size_t)(r & 15) * 16);

  u64 tk[TOPK];
  #pragma unroll
  for (int i = 0; i < TOPK; ++i) tk[i] = 0;

  for (int col = lane; col < N_GLB; col += 64) {
    const char* gp = wsg2 + (size_t)(col >> 4) * 4096 + (size_t)(col & 15) * 16;
    float acc = 0.f;
    #pragma unroll
    for (int c = 0; c < 16; ++c) {
      uint4 gv = *(const uint4*)(gp + c * 256);
      uint4 fc = fr[c];
      #pragma unroll
      for (int p = 0; p < 4; ++p) {
        unsigned fa = (&fc.x)[p], ga = (&gv.x)[p];
        acc += __uint_as_float(fa << 16) * __uint_as_float(ga << 16)
             + __uint_as_float(fa & 0xFFFF0000u) * __uint_as_float(ga & 0xFFFF0000u);
      }
    }
    u64 key = mkkey(acc, col);
    if (key > tk[0]) {
      u64 cur = key;
      #pragma unroll
      for (int i = 0; i < TOPK - 1; ++i) {
        u64 nxt = tk[i + 1];
        u64 lo = cur < nxt ? cur : nxt;
        u64 hi = cur < nxt ? nxt : cur;
        tk[i] = lo; cur = hi;
      }
      tk[TOPK - 1] = cur;
    }
  }

  int rc = fclust[r];
  float S10 = 0.f, C10 = 0.f;
  for (int it = 0; it < TOPK; ++it) {
    u64 best = tk[TOPK - 1];
    #pragma unroll
    for (int m = 32; m; m >>= 1) best = umax64(best, __shfl_xor(best, m));
    float val = fmono_inv((unsigned)(best >> 32)) * LN2;
    int col = (int)(~(unsigned)(best & 0xFFFFFFFFull));
    if (gclust[col] != rc) { S10 += val; C10 += 1.f; }
    if (tk[TOPK - 1] == best) {
      #pragma unroll
      for (int i = TOPK - 1; i > 0; --i) tk[i] = tk[i - 1];
      tk[0] = 0;
    }
  }

  float sev = (lane < NSPLIT) ? p_se[(size_t)r * NSPLIT + lane] : 0.f;
  sev += __shfl_xor(sev, 8); sev += __shfl_xor(sev, 4);
  sev += __shfl_xor(sev, 2); sev += __shfl_xor(sev, 1);
  sev = __shfl(sev, 0);
  float2 fv = ((const float2*)(f + (size_t)r * DDIM))[lane];
  float scf = inv_fT[r];
  int ia = 0, ib = 0, hc = 0;
  #pragma unroll
  for (int s = 0; s < NSLICE; ++s) {
    ia += csum_i32[(size_t)s * NCLUST * DDIM + rc * DDIM + 2 * lane];
    ib += csum_i32[(size_t)s * NCLUST * DDIM + rc * DDIM + 2 * lane + 1];
    hc += hist8[s * 128 + rc];
  }
  float dt = fv.x * scf * (ia * INV_CSC) + fv.y * scf * (ib * INV_CSC);
  #pragma unroll
  for (int m = 32; m; m >>= 1) dt += __shfl_xor(dt, m);
  if (lane == 0) {
    float L = logf(sev + 1e-12f);
    float C = (float)hc + C10;
    rowv[r] = (dt + S10 - C * L) / (C + 1e-12f);
  }
}

__global__ void final_kernel(const float* __restrict__ rowv, float* __restrict__ out) {
  __shared__ float sm[256];
  int t = threadIdx.x;
  float s = 0.f;
  for (int i = t; i < B_ROWS; i += 256) s += rowv[i];
  sm[t] = s;
  __syncthreads();
  for (int o = 128; o; o >>= 1) { if (t < o) sm[t] += sm[t + o]; __syncthreads(); }
  if (t == 0) out[0] = -(sm[0] / (float)B_ROWS);
}

extern "C" void kernel_launch(void* const* d_in, const int* in_sizes, int n_in,
                              void* d_out, int out_size, void* d_ws, size_t ws_size,
                              hipStream_t stream) {
  const float* f  = (const float*)d_in[0];
  const int*   fc = (const int*)  d_in[1];
  const float* g  = (const float*)d_in[2];
  const int*   gc = (const int*)  d_in[3];
  float* out = (float*)d_out;

  char* ws = (char*)d_ws;
  char*  wsf2    = ws;                          // 512 KB
  char*  wsg2    = ws + 524288;                 // 16 MB -> 17301504
  float* inv_fT  = (float*)(ws + 17301504);     // 8 KB  -> 17309696
  float* p_se    = (float*)(ws + 17309696);     // 128 KB-> 17440768
  // zeroed block [17440768, 17870848): csum 400KB + hist8 4KB + cnt 8KB + flags 8KB
  int*   csum_i32= (int*)  (ws + 17440768);     // 8*100*128*4 = 409600
  int*   hist8   = (int*)  (ws + 17850368);     // 8*128*4 = 4096
  int*   cnt     = (int*)  (ws + 17854464);     // 8192
  int*   flags   = (int*)  (ws + 17862656);     // 8192 -> 17870848
  float* lv      = (float*)(ws + 17870848);     // 2 MB -> 19968000
  int*   li      = (int*)  (ws + 19968000);     // 2 MB -> 22065152
  float* rowv    = (float*)(ws + 22065152);     // 8 KB (total ~22.1 MB)

  hipMemsetAsync(ws + 17440768, 0, 430080, stream);

  prep_kernel<<<(B_ROWS + N_GLB) / 4, 256, 0, stream>>>(f, g, gc, wsf2, wsg2,
                                                        inv_fT, csum_i32, hist8);

  dim3 grid(NSPLIT, B_ROWS / 64);   // x=chunk, y=row-block
  sim_kernel<<<grid, 256, 0, stream>>>(wsf2, wsg2, p_se, lv, li, cnt);

  merge_kernel<<<B_ROWS / 4, 256, 0, stream>>>(f, fc, gc, inv_fT, p_se, csum_i32,
                                               hist8, lv, li, cnt, flags, rowv);
  fallback_kernel<<<B_ROWS / 4, 256, 0, stream>>>(f, fc, gc, inv_fT, p_se, csum_i32,
                                                  hist8, wsf2, wsg2, flags, rowv);
  final_kernel<<<1, 256, 0, stream>>>(rowv, out);
}